// Round 11
// baseline (1397.845 us; speedup 1.0000x reference)
//
#include <hip/hip_runtime.h>
#include <hip/hip_cooperative_groups.h>
#include <hip/hip_bf16.h>
#include <cstddef>
#include <cstdint>

#define NNODES 500000
#define DIM    128
#define NSEG   8192
#define TSTEPS 6
#define WCHUNK 32

namespace cg = cooperative_groups;

typedef __attribute__((ext_vector_type(8))) short bf16x8;
typedef __attribute__((ext_vector_type(4))) float f32x4;
typedef unsigned short ushort_t;

static __device__ inline ushort_t f2bf_u(float f) {
    __hip_bfloat16 h = __float2bfloat16(f);
    return *reinterpret_cast<ushort_t*>(&h);
}
static __device__ inline float bfu2f(ushort_t u) {
    union { unsigned i; float f; } c; c.i = ((unsigned)u) << 16; return c.f;
}
#define LGKM_WAIT() __asm__ __volatile__("s_waitcnt lgkmcnt(0)" ::: "memory")

// LDS layout (union of phases), 18192 B total:
//   gemm: As[0..8192) Bs[8192..12288)
//   attn: xs[0..16384) es[16384..16640) mstat[16640..16656)
//         rb[16656..17680) hsh[17680..18192)
#define SMEM_BYTES 18192

__global__ __launch_bounds__(128) void set2set_coop_k(
    const float* __restrict__ x, ushort_t* __restrict__ xbf,
    const int* __restrict__ batch,
    const float* __restrict__ Wih, const float* __restrict__ Whh,
    const float* __restrict__ bih, const float* __restrict__ bhh,
    float* __restrict__ cbuf, float* __restrict__ gates,
    __hip_bfloat16* __restrict__ abuf, __hip_bfloat16* __restrict__ wbuf,
    int* __restrict__ seg, float* __restrict__ qstar,
    int use_xbf, int nblk)
{
    cg::grid_group grid = cg::this_grid();
    __shared__ alignas(16) char smem[SMEM_BYTES];

    const int tid = threadIdx.x;
    const int gid = blockIdx.x;
    const int gthreads = nblk * 128;
    const int gtid = gid * 128 + tid;

    // ---- phase 0: weight conversion + segment bounds
    for (int idx = gtid; idx < 512 * 384; idx += gthreads) {
        int n = idx / 384, k = idx - n * 384;
        float v = (k < 256) ? Wih[n * 256 + k] : Whh[n * 128 + (k - 256)];
        wbuf[idx] = __float2bfloat16(v);
    }
    for (int b = gtid; b <= NSEG; b += gthreads) {
        int lo = 0, hi = NNODES;
        while (lo < hi) { int mid = (lo + hi) >> 1; if (batch[mid] < b) lo = mid + 1; else hi = mid; }
        seg[b] = lo;
    }
    grid.sync();

    const int lane = tid & 63, wv = tid >> 6;
    const int l16 = lane & 15, grp = lane >> 4;

    for (int t = 0; t < TSTEPS; ++t) {
        // =================== GEMM phase (t>0): gates = Abf @ Wbf^T ==========
        if (t > 0) {
            char* As = smem;          // 64 rows x 128 B
            char* Bs = smem + 8192;   // 32 rows x 128 B
            const int ar = tid >> 1, acb = (tid & 1) * 64, amask = (ar & 7) << 4;
            const int br = tid >> 2, bcb = (tid & 3) * 32, bmask = (br & 7) << 4;
            for (int tile = gid; tile < 2048; tile += nblk) {
                const int n0 = (tile & 15) * 32;
                const int m0 = (tile >> 4) * 64;
                f32x4 acc[2][2] = {};
                for (int s = 0; s < 6; ++s) {
                    __syncthreads();
                    const char* aP = (const char*)(abuf + (size_t)(m0 + ar) * 384) + s * 128 + acb;
                    #pragma unroll
                    for (int c = 0; c < 4; ++c)
                        *(int4*)(As + ar * 128 + ((acb + c * 16) ^ amask)) = *(const int4*)(aP + c * 16);
                    const char* bP = (const char*)(wbuf + (size_t)(n0 + br) * 384) + s * 128 + bcb;
                    #pragma unroll
                    for (int c = 0; c < 2; ++c)
                        *(int4*)(Bs + br * 128 + ((bcb + c * 16) ^ bmask)) = *(const int4*)(bP + c * 16);
                    __syncthreads();
                    #pragma unroll
                    for (int ks = 0; ks < 2; ++ks) {
                        const int kb = ks * 64 + ((lane >> 4) << 4);
                        bf16x8 af[2], bfr[2];
                        #pragma unroll
                        for (int rbk = 0; rbk < 2; ++rbk) {
                            int r = wv * 32 + rbk * 16 + l16;
                            af[rbk] = *(const bf16x8*)(As + r * 128 + (kb ^ ((r & 7) << 4)));
                        }
                        #pragma unroll
                        for (int cb = 0; cb < 2; ++cb) {
                            int n = cb * 16 + l16;
                            bfr[cb] = *(const bf16x8*)(Bs + n * 128 + (kb ^ ((n & 7) << 4)));
                        }
                        #pragma unroll
                        for (int rbk = 0; rbk < 2; ++rbk)
                            #pragma unroll
                            for (int cb = 0; cb < 2; ++cb)
                                acc[rbk][cb] = __builtin_amdgcn_mfma_f32_16x16x32_bf16(
                                    af[rbk], bfr[cb], acc[rbk][cb], 0, 0, 0);
                    }
                }
                const int rowb = (lane >> 4) << 2;
                #pragma unroll
                for (int rbk = 0; rbk < 2; ++rbk)
                    #pragma unroll
                    for (int cb = 0; cb < 2; ++cb) {
                        int row = m0 + wv * 32 + rbk * 16 + rowb;
                        int col = n0 + cb * 16 + l16;
                        float* gp = gates + (size_t)row * 512 + col;
                        #pragma unroll
                        for (int reg = 0; reg < 4; ++reg)
                            gp[(size_t)reg * 512] = acc[rbk][cb][reg];
                    }
            }
            grid.sync();
        }

        // =================== LSTM + attention phase =========================
        const int t0f      = (t == 0) ? 1 : 0;
        const int read_bf  = (use_xbf && t > 0) ? 1 : 0;
        const int write_bf = (use_xbf && t == 0) ? 1 : 0;
        ushort_t* xs = (ushort_t*)smem;
        float* es    = (float*)(smem + 16384);
        float* mstat = (float*)(smem + 16640);
        float* rb    = (float*)(smem + 16656);
        float* hsh   = (float*)(smem + 17680);
        ushort_t* xw = xs + wv * (WCHUNK * 128);
        float*    ew = es + wv * WCHUNK;

        for (int b = gid; b < NSEG; b += nblk) {
            // ---- LSTM prologue: dim d = tid
            {
                const int d = tid;
                float gi, gf, gg, go;
                if (t0f) {
                    gi = bih[d]       + bhh[d];
                    gf = bih[128 + d] + bhh[128 + d];
                    gg = bih[256 + d] + bhh[256 + d];
                    go = bih[384 + d] + bhh[384 + d];
                } else {
                    const float* g = gates + (size_t)b * 512;
                    gi = g[d]       + bih[d]       + bhh[d];
                    gf = g[128 + d] + bih[128 + d] + bhh[128 + d];
                    gg = g[256 + d] + bih[256 + d] + bhh[256 + d];
                    go = g[384 + d] + bih[384 + d] + bhh[384 + d];
                }
                float iv = 1.f / (1.f + expf(-gi));
                float fv = 1.f / (1.f + expf(-gf));
                float gv = tanhf(gg);
                float ov = 1.f / (1.f + expf(-go));
                float cp = t0f ? 0.f : cbuf[(size_t)b * 128 + d];
                float c  = fv * cp + iv * gv;
                float h  = ov * tanhf(c);
                cbuf[(size_t)b * 128 + d] = c;
                qstar[(size_t)b * 256 + d] = h;
                __hip_bfloat16 hb = __float2bfloat16(h);
                abuf[(size_t)b * 384 + d] = hb;
                abuf[(size_t)b * 384 + 256 + d] = hb;
                hsh[d] = h;
            }
            __syncthreads();

            const int ns = seg[b], ne = seg[b + 1];
            if (ns >= ne) {
                qstar[(size_t)b * 256 + DIM + tid] = 0.f;
                abuf[(size_t)b * 384 + 128 + tid] = __float2bfloat16(0.f);
                continue;
            }

            float4 h0, h1, hA, hB;
            if (read_bf) {
                hA = *(const float4*)&hsh[8 * l16];
                hB = *(const float4*)&hsh[8 * l16 + 4];
            } else {
                h0 = *(const float4*)&hsh[4 * l16];
                h1 = *(const float4*)&hsh[64 + 4 * l16];
            }

            float m = -INFINITY, den = 0.f, r0 = 0.f, r1 = 0.f;
            const int d0 = 2 * lane;

            for (int c0 = ns + wv * WCHUNK; c0 < ne; c0 += 2 * WCHUNK) {
                const int cc = min(WCHUNK, ne - c0);

                LGKM_WAIT();   // prior chunk's LDS reads drained before overwrite
                if (read_bf) {
                    if (cc == WCHUNK) {
                        #pragma unroll
                        for (int it = 0; it < WCHUNK / 8; ++it) {
                            const int raw = grp + it * 8, rbw = raw + 4;
                            int4 v0 = *(const int4*)(xbf + (size_t)(c0 + raw) * 128 + 8 * l16);
                            int4 v1 = *(const int4*)(xbf + (size_t)(c0 + rbw) * 128 + 8 * l16);
                            {
                                *(int4*)(&xw[raw * 128 + 8 * l16]) = v0;
                                const ushort_t* u = (const ushort_t*)&v0;
                                float s = bfu2f(u[0])*hA.x + bfu2f(u[1])*hA.y
                                        + bfu2f(u[2])*hA.z + bfu2f(u[3])*hA.w
                                        + bfu2f(u[4])*hB.x + bfu2f(u[5])*hB.y
                                        + bfu2f(u[6])*hB.z + bfu2f(u[7])*hB.w;
                                s += __shfl_xor(s, 1); s += __shfl_xor(s, 2);
                                s += __shfl_xor(s, 4); s += __shfl_xor(s, 8);
                                if (l16 == 0) ew[raw] = s;
                            }
                            {
                                *(int4*)(&xw[rbw * 128 + 8 * l16]) = v1;
                                const ushort_t* u = (const ushort_t*)&v1;
                                float s = bfu2f(u[0])*hA.x + bfu2f(u[1])*hA.y
                                        + bfu2f(u[2])*hA.z + bfu2f(u[3])*hA.w
                                        + bfu2f(u[4])*hB.x + bfu2f(u[5])*hB.y
                                        + bfu2f(u[6])*hB.z + bfu2f(u[7])*hB.w;
                                s += __shfl_xor(s, 1); s += __shfl_xor(s, 2);
                                s += __shfl_xor(s, 4); s += __shfl_xor(s, 8);
                                if (l16 == 0) ew[rbw] = s;
                            }
                        }
                    } else {
                        for (int j = c0 + grp; j < c0 + cc; j += 4) {
                            const int row = j - c0;
                            int4 v = *(const int4*)(xbf + (size_t)j * 128 + 8 * l16);
                            *(int4*)(&xw[row * 128 + 8 * l16]) = v;
                            const ushort_t* u = (const ushort_t*)&v;
                            float s = bfu2f(u[0])*hA.x + bfu2f(u[1])*hA.y
                                    + bfu2f(u[2])*hA.z + bfu2f(u[3])*hA.w
                                    + bfu2f(u[4])*hB.x + bfu2f(u[5])*hB.y
                                    + bfu2f(u[6])*hB.z + bfu2f(u[7])*hB.w;
                            s += __shfl_xor(s, 1); s += __shfl_xor(s, 2);
                            s += __shfl_xor(s, 4); s += __shfl_xor(s, 8);
                            if (l16 == 0) ew[row] = s;
                        }
                    }
                } else {
                    for (int j = c0 + grp; j < c0 + cc; j += 4) {
                        const int row = j - c0;
                        const float4* xp = (const float4*)(x + (size_t)j * DIM);
                        float4 xa = xp[l16], xb = xp[l16 + 16];
                        float s = xa.x*h0.x + xa.y*h0.y + xa.z*h0.z + xa.w*h0.w
                                + xb.x*h1.x + xb.y*h1.y + xb.z*h1.z + xb.w*h1.w;
                        s += __shfl_xor(s, 1); s += __shfl_xor(s, 2);
                        s += __shfl_xor(s, 4); s += __shfl_xor(s, 8);
                        uint2 pa, pb;
                        pa.x = (unsigned)f2bf_u(xa.x) | ((unsigned)f2bf_u(xa.y) << 16);
                        pa.y = (unsigned)f2bf_u(xa.z) | ((unsigned)f2bf_u(xa.w) << 16);
                        pb.x = (unsigned)f2bf_u(xb.x) | ((unsigned)f2bf_u(xb.y) << 16);
                        pb.y = (unsigned)f2bf_u(xb.z) | ((unsigned)f2bf_u(xb.w) << 16);
                        *(uint2*)(&xw[row * 128 + 4 * l16])      = pa;
                        *(uint2*)(&xw[row * 128 + 64 + 4 * l16]) = pb;
                        if (write_bf) {
                            *(uint2*)(xbf + (size_t)j * 128 + 4 * l16)      = pa;
                            *(uint2*)(xbf + (size_t)j * 128 + 64 + 4 * l16) = pb;
                        }
                        if (l16 == 0) ew[row] = s;
                    }
                }
                LGKM_WAIT();   // es/xs writes visible to whole wave

                const int idx = lane & 31;
                float cm = (idx < cc) ? ew[idx] : -INFINITY;
                #pragma unroll
                for (int o = 1; o < 64; o <<= 1) cm = fmaxf(cm, __shfl_xor(cm, o));

                const float mn = fmaxf(m, cm);
                const float scale = expf(m - mn);

                float w = 0.f;
                if (lane < 32 && lane < cc) {
                    w = expf(ew[lane] - mn);
                    ew[lane] = w;
                }
                float cd = w;
                #pragma unroll
                for (int o = 1; o < 64; o <<= 1) cd += __shfl_xor(cd, o);
                LGKM_WAIT();   // exp'd es visible before pass 3 reads

                den = den * scale + cd;
                r0 *= scale;
                r1 *= scale;

                #pragma unroll 4
                for (int row = 0; row < cc; ++row) {
                    float wr = ew[row];
                    unsigned p = *(const unsigned*)(&xw[row * 128 + d0]);
                    r0 = fmaf(wr, bfu2f((ushort_t)(p & 0xffff)), r0);
                    r1 = fmaf(wr, bfu2f((ushort_t)(p >> 16)), r1);
                }

                m = mn;
            }

            // ---- cross-wave merge
            if (lane == 0) { mstat[wv * 2 + 0] = m; mstat[wv * 2 + 1] = den; }
            rb[wv * 128 + d0]     = r0;
            rb[wv * 128 + d0 + 1] = r1;
            __syncthreads();
            {
                const float m0s = mstat[0], dn0 = mstat[1];
                const float m1s = mstat[2], dn1 = mstat[3];
                const float ms  = fmaxf(m0s, m1s);
                const float k0  = expf(m0s - ms);
                const float k1  = expf(m1s - ms);
                const float dtot = k0 * dn0 + k1 * dn1;
                const float rv = (k0 * rb[tid] + k1 * rb[128 + tid]) / (dtot + 1e-16f);
                qstar[(size_t)b * 256 + DIM + tid] = rv;
                abuf[(size_t)b * 384 + 128 + tid] = __float2bfloat16(rv);
            }
        }
        if (t < TSTEPS - 1) grid.sync();
    }
}

// ---------------------------------------------------------------------------
extern "C" void kernel_launch(void* const* d_in, const int* in_sizes, int n_in,
                              void* d_out, int out_size, void* d_ws, size_t ws_size,
                              hipStream_t stream) {
    const float* x     = (const float*)d_in[0];
    const int*   batch = (const int*)d_in[1];
    const float* Wih   = (const float*)d_in[2];
    const float* Whh   = (const float*)d_in[3];
    const float* bih   = (const float*)d_in[4];
    const float* bhh   = (const float*)d_in[5];
    float* out = (float*)d_out;

    // workspace layout
    float* cbuf  = (float*)d_ws;                            // 8192*128 f32
    float* gates = cbuf + (size_t)NSEG * DIM;               // 8192*512 f32
    __hip_bfloat16* abuf = (__hip_bfloat16*)(gates + (size_t)NSEG * 512);  // 8192*384
    __hip_bfloat16* wbuf = abuf + (size_t)NSEG * 384;       // 512*384
    int* seg = (int*)(wbuf + (size_t)512 * 384);
    size_t fixed_bytes = (size_t)((char*)(seg + NSEG + 1) - (char*)d_ws);
    size_t xbf_off = (fixed_bytes + 15) & ~(size_t)15;
    ushort_t* xbf = (ushort_t*)((char*)d_ws + xbf_off);
    size_t need = xbf_off + (size_t)NNODES * DIM * sizeof(ushort_t);
    int use_xbf = (ws_size >= need) ? 1 : 0;

    // grid size: guaranteed co-resident for cooperative launch
    int maxb = 0;
    hipOccupancyMaxActiveBlocksPerMultiprocessor(&maxb, set2set_coop_k, 128, 0);
    if (maxb < 1) maxb = 1;
    int ncu = 0;
    hipDeviceGetAttribute(&ncu, hipDeviceAttributeMultiprocessorCount, 0);
    if (ncu < 1) ncu = 256;
    int nblk = maxb * ncu;
    if (nblk > 2048) nblk = 2048;

    void* args[] = {
        (void*)&x, (void*)&xbf, (void*)&batch,
        (void*)&Wih, (void*)&Whh, (void*)&bih, (void*)&bhh,
        (void*)&cbuf, (void*)&gates, (void*)&abuf, (void*)&wbuf,
        (void*)&seg, (void*)&out, (void*)&use_xbf, (void*)&nblk
    };
    hipLaunchCooperativeKernel((const void*)set2set_coop_k,
                               dim3(nblk), dim3(128), args, 0, stream);
}

// Round 12
// 394.533 us; speedup vs baseline: 3.5430x; 3.5430x over previous
//
#include <hip/hip_runtime.h>
#include <hip/hip_bf16.h>
#include <cstddef>
#include <cstdint>

#define NNODES 500000
#define DIM    128
#define NSEG   8192
#define TSTEPS 6

typedef __attribute__((ext_vector_type(8))) short bf16x8;
typedef __attribute__((ext_vector_type(4))) float f32x4;
typedef unsigned short ushort_t;

static __device__ inline ushort_t f2bf_u(float f) {
    __hip_bfloat16 h = __float2bfloat16(f);
    return *reinterpret_cast<ushort_t*>(&h);
}
static __device__ inline float bfu2f(ushort_t u) {
    union { unsigned i; float f; } c; c.i = ((unsigned)u) << 16; return c.f;
}

// ---------------------------------------------------------------------------
// Segment bounds: batch is sorted; seg[b] = lower_bound(batch, b), seg[B] = N.
// ---------------------------------------------------------------------------
__global__ void seg_bounds_k(const int* __restrict__ batch, int* __restrict__ seg, int n) {
    int b = blockIdx.x * blockDim.x + threadIdx.x;
    if (b > NSEG) return;
    int lo = 0, hi = n;
    while (lo < hi) {
        int mid = (lo + hi) >> 1;
        if (batch[mid] < b) lo = mid + 1; else hi = mid;
    }
    seg[b] = lo;
}

// ---------------------------------------------------------------------------
// One-time: wbuf[n][k] bf16, k<256 from Wih[n][k], else Whh[n][k-256].
// ---------------------------------------------------------------------------
__global__ __launch_bounds__(256) void wconv_k(
    const float* __restrict__ Wih, const float* __restrict__ Whh,
    __hip_bfloat16* __restrict__ wbuf)
{
    int idx = blockIdx.x * 256 + threadIdx.x;    // 512*384 exact
    int n = idx / 384, k = idx - n * 384;
    float v = (k < 256) ? Wih[n * 256 + k] : Whh[n * 128 + (k - 256)];
    wbuf[idx] = __float2bfloat16(v);
}

// ---------------------------------------------------------------------------
// gates = Abf @ Wbf^T  (fp32 accumulate). A=[8192][384] bf16 = [q|r|h],
// W=[512][384] bf16. MFMA 16x16x32, BM=128 BN=64 BK=64, 4 waves (2x2).
// ---------------------------------------------------------------------------
__global__ __launch_bounds__(256) void gemm_mfma_k(
    const __hip_bfloat16* __restrict__ abuf,
    const __hip_bfloat16* __restrict__ wbuf,
    float* __restrict__ gates)
{
    __shared__ char As[128 * 128];
    __shared__ char Bs[64 * 128];
    const int tid  = threadIdx.x;
    const int lane = tid & 63, wave = tid >> 6;
    const int wrow = (wave >> 1) * 64;
    const int wcol = (wave & 1) * 32;
    const int m0 = blockIdx.y * 128;
    const int n0 = blockIdx.x * 64;

    const int ar  = tid >> 1;
    const int acb = (tid & 1) * 64;
    const int br  = tid >> 2;
    const int bcb = (tid & 3) * 32;

    const char* aP = (const char*)(abuf + (size_t)(m0 + ar) * 384) + acb;
    const char* bP = (const char*)(wbuf + (size_t)(n0 + br) * 384) + bcb;

    f32x4 acc[4][2] = {};

    int4 ra[4]; int4 rb2[2];
    #pragma unroll
    for (int c = 0; c < 4; ++c) ra[c]  = *(const int4*)(aP + c * 16);
    #pragma unroll
    for (int c = 0; c < 2; ++c) rb2[c] = *(const int4*)(bP + c * 16);

    char* asw = As + ar * 128;
    char* bsw = Bs + br * 128;
    const int amask = (ar & 7) << 4;
    const int bmask = (br & 7) << 4;

    for (int s = 0; s < 6; ++s) {
        __syncthreads();
        #pragma unroll
        for (int c = 0; c < 4; ++c)
            *(int4*)(asw + ((acb + c * 16) ^ amask)) = ra[c];
        #pragma unroll
        for (int c = 0; c < 2; ++c)
            *(int4*)(bsw + ((bcb + c * 16) ^ bmask)) = rb2[c];
        __syncthreads();

        if (s < 5) {
            const char* aN = aP + (size_t)(s + 1) * 128;
            const char* bN = bP + (size_t)(s + 1) * 128;
            #pragma unroll
            for (int c = 0; c < 4; ++c) ra[c]  = *(const int4*)(aN + c * 16);
            #pragma unroll
            for (int c = 0; c < 2; ++c) rb2[c] = *(const int4*)(bN + c * 16);
        }

        #pragma unroll
        for (int ks = 0; ks < 2; ++ks) {
            const int kb = ks * 64 + ((lane >> 4) << 4);
            bf16x8 af[4], bfr[2];
            #pragma unroll
            for (int rbk = 0; rbk < 4; ++rbk) {
                int r = wrow + rbk * 16 + (lane & 15);
                af[rbk] = *(const bf16x8*)(As + r * 128 + (kb ^ ((r & 7) << 4)));
            }
            #pragma unroll
            for (int cb = 0; cb < 2; ++cb) {
                int n = wcol + cb * 16 + (lane & 15);
                bfr[cb] = *(const bf16x8*)(Bs + n * 128 + (kb ^ ((n & 7) << 4)));
            }
            #pragma unroll
            for (int rbk = 0; rbk < 4; ++rbk)
                #pragma unroll
                for (int cb = 0; cb < 2; ++cb)
                    acc[rbk][cb] = __builtin_amdgcn_mfma_f32_16x16x32_bf16(
                        af[rbk], bfr[cb], acc[rbk][cb], 0, 0, 0);
        }
    }

    const int rowb = (lane >> 4) << 2;
    const int coll = lane & 15;
    #pragma unroll
    for (int rbk = 0; rbk < 4; ++rbk)
        #pragma unroll
        for (int cb = 0; cb < 2; ++cb) {
            int row = m0 + wrow + rbk * 16 + rowb;
            int col = n0 + wcol + cb * 16 + coll;
            float* gp = gates + (size_t)row * 512 + col;
            #pragma unroll
            for (int reg = 0; reg < 4; ++reg)
                gp[(size_t)reg * 512] = acc[rbk][cb][reg];
        }
}

// ---------------------------------------------------------------------------
// Fused LSTM + flash-style attention. Block = segment b (128 thr, 2 waves).
// LSTM prologue (thread=dim) -> h in LDS. Then 8 groups of 16 lanes stream
// rows (group g: rows ns+g, ns+g+8, ...). Per row: one int4 load (lane's 8
// dims), dot via 4 shfls, branchless online-softmax rescale into REGISTER
// accumulators racc[8]. No LDS, no waitcnt in the loop; depth-2 pipeline.
// One LDS merge of the 8 group states at segment end.
// ---------------------------------------------------------------------------
__global__ __launch_bounds__(128) void attn_lstm_k(
    const float* __restrict__ x, ushort_t* __restrict__ xbf,
    const int* __restrict__ seg, const float* __restrict__ gates,
    const float* __restrict__ bih, const float* __restrict__ bhh,
    float* __restrict__ cbuf, float* __restrict__ qstar,
    __hip_bfloat16* __restrict__ abuf,
    int t0, int read_bf, int write_bf)
{
    const int tid  = threadIdx.x;
    const int wv   = tid >> 6, lane = tid & 63;
    const int b    = blockIdx.x;
    const int l16  = lane & 15;
    const int ggrp = (wv << 2) | (lane >> 4);   // 0..7

    __shared__ float hsh[128];
    __shared__ float gm[8], gden[8];
    __shared__ float racc_s[8][128];

    // ---- LSTM prologue: dim d = tid
    {
        const int d = tid;
        float gi, gf, gg, go;
        if (t0) {
            gi = bih[d]       + bhh[d];
            gf = bih[128 + d] + bhh[128 + d];
            gg = bih[256 + d] + bhh[256 + d];
            go = bih[384 + d] + bhh[384 + d];
        } else {
            const float* g = gates + (size_t)b * 512;
            gi = g[d]       + bih[d]       + bhh[d];
            gf = g[128 + d] + bih[128 + d] + bhh[128 + d];
            gg = g[256 + d] + bih[256 + d] + bhh[256 + d];
            go = g[384 + d] + bih[384 + d] + bhh[384 + d];
        }
        float iv = 1.f / (1.f + expf(-gi));
        float fv = 1.f / (1.f + expf(-gf));
        float gv = tanhf(gg);
        float ov = 1.f / (1.f + expf(-go));
        float cp = t0 ? 0.f : cbuf[(size_t)b * 128 + d];
        float c  = fv * cp + iv * gv;
        float h  = ov * tanhf(c);
        cbuf[(size_t)b * 128 + d] = c;
        qstar[(size_t)b * 256 + d] = h;
        __hip_bfloat16 hb = __float2bfloat16(h);
        abuf[(size_t)b * 384 + d] = hb;
        abuf[(size_t)b * 384 + 256 + d] = hb;
        hsh[d] = h;
    }
    __syncthreads();

    const int ns = seg[b], ne = seg[b + 1];
    if (ns >= ne) {
        qstar[(size_t)b * 256 + DIM + tid] = 0.f;
        abuf[(size_t)b * 384 + 128 + tid] = __float2bfloat16(0.f);
        return;
    }

    // lane's 8 dims: [8*l16, 8*l16+8)
    float hreg[8];
    #pragma unroll
    for (int i = 0; i < 8; ++i) hreg[i] = hsh[8 * l16 + i];

    float m = -INFINITY, den = 0.f;
    float racc[8] = {};

    if (read_bf) {
        int j = ns + ggrp;
        if (j < ne) {
            int4 v = *(const int4*)(xbf + (size_t)j * 128 + 8 * l16);
            for (int jn = j + 8; ; jn += 8) {
                const bool more = (jn < ne);
                int4 vn;
                if (more) vn = *(const int4*)(xbf + (size_t)jn * 128 + 8 * l16);
                // process v
                const ushort_t* u = (const ushort_t*)&v;
                float xv[8];
                #pragma unroll
                for (int i = 0; i < 8; ++i) xv[i] = bfu2f(u[i]);
                float s = xv[0]*hreg[0] + xv[1]*hreg[1] + xv[2]*hreg[2] + xv[3]*hreg[3]
                        + xv[4]*hreg[4] + xv[5]*hreg[5] + xv[6]*hreg[6] + xv[7]*hreg[7];
                s += __shfl_xor(s, 1); s += __shfl_xor(s, 2);
                s += __shfl_xor(s, 4); s += __shfl_xor(s, 8);
                const float mn = fmaxf(m, s);
                const float scale = expf(m - mn);    // first row: exp(-inf)=0
                const float w = expf(s - mn);
                den = den * scale + w;
                #pragma unroll
                for (int i = 0; i < 8; ++i) racc[i] = fmaf(racc[i], scale, w * xv[i]);
                m = mn;
                if (!more) break;
                v = vn;
            }
        }
    } else {
        int j = ns + ggrp;
        if (j < ne) {
            const float4* xp = (const float4*)(x + (size_t)j * DIM + 8 * l16);
            float4 va = xp[0], vb = xp[1];
            for (int jn = j + 8; ; jn += 8) {
                const bool more = (jn < ne);
                float4 na, nb;
                if (more) {
                    const float4* xn = (const float4*)(x + (size_t)jn * DIM + 8 * l16);
                    na = xn[0]; nb = xn[1];
                }
                float xv[8] = {va.x, va.y, va.z, va.w, vb.x, vb.y, vb.z, vb.w};
                if (write_bf) {
                    int4 pk;
                    unsigned* pu = (unsigned*)&pk;
                    pu[0] = (unsigned)f2bf_u(xv[0]) | ((unsigned)f2bf_u(xv[1]) << 16);
                    pu[1] = (unsigned)f2bf_u(xv[2]) | ((unsigned)f2bf_u(xv[3]) << 16);
                    pu[2] = (unsigned)f2bf_u(xv[4]) | ((unsigned)f2bf_u(xv[5]) << 16);
                    pu[3] = (unsigned)f2bf_u(xv[6]) | ((unsigned)f2bf_u(xv[7]) << 16);
                    *(int4*)(xbf + (size_t)(jn - 8) * 128 + 8 * l16) = pk;
                }
                float s = xv[0]*hreg[0] + xv[1]*hreg[1] + xv[2]*hreg[2] + xv[3]*hreg[3]
                        + xv[4]*hreg[4] + xv[5]*hreg[5] + xv[6]*hreg[6] + xv[7]*hreg[7];
                s += __shfl_xor(s, 1); s += __shfl_xor(s, 2);
                s += __shfl_xor(s, 4); s += __shfl_xor(s, 8);
                const float mn = fmaxf(m, s);
                const float scale = expf(m - mn);
                const float w = expf(s - mn);
                den = den * scale + w;
                #pragma unroll
                for (int i = 0; i < 8; ++i) racc[i] = fmaf(racc[i], scale, w * xv[i]);
                m = mn;
                if (!more) break;
                va = na; vb = nb;
            }
        }
    }

    // ---- merge 8 group states
    if (l16 == 0) { gm[ggrp] = m; gden[ggrp] = den; }
    *(float4*)&racc_s[ggrp][8 * l16]     = make_float4(racc[0], racc[1], racc[2], racc[3]);
    *(float4*)&racc_s[ggrp][8 * l16 + 4] = make_float4(racc[4], racc[5], racc[6], racc[7]);
    __syncthreads();

    {
        float mM = gm[0];
        #pragma unroll
        for (int g = 1; g < 8; ++g) mM = fmaxf(mM, gm[g]);
        float dtot = 0.f, rtot = 0.f;
        #pragma unroll
        for (int g = 0; g < 8; ++g) {
            const float k = expf(gm[g] - mM);   // -inf group -> 0
            dtot = fmaf(k, gden[g], dtot);
            rtot = fmaf(k, racc_s[g][tid], rtot);
        }
        const float rv = rtot / (dtot + 1e-16f);
        qstar[(size_t)b * 256 + DIM + tid] = rv;
        abuf[(size_t)b * 384 + 128 + tid] = __float2bfloat16(rv);
    }
}

// ---------------------------------------------------------------------------
extern "C" void kernel_launch(void* const* d_in, const int* in_sizes, int n_in,
                              void* d_out, int out_size, void* d_ws, size_t ws_size,
                              hipStream_t stream) {
    const float* x     = (const float*)d_in[0];
    const int*   batch = (const int*)d_in[1];
    const float* Wih   = (const float*)d_in[2];
    const float* Whh   = (const float*)d_in[3];
    const float* bih   = (const float*)d_in[4];
    const float* bhh   = (const float*)d_in[5];
    float* out = (float*)d_out;

    // workspace layout
    float* cbuf  = (float*)d_ws;                            // 8192*128 f32
    float* gates = cbuf + (size_t)NSEG * DIM;               // 8192*512 f32
    __hip_bfloat16* abuf = (__hip_bfloat16*)(gates + (size_t)NSEG * 512);  // 8192*384
    __hip_bfloat16* wbuf = abuf + (size_t)NSEG * 384;       // 512*384
    int* seg = (int*)(wbuf + (size_t)512 * 384);
    size_t fixed_bytes = (size_t)((char*)(seg + NSEG + 1) - (char*)d_ws);
    size_t xbf_off = (fixed_bytes + 15) & ~(size_t)15;
    ushort_t* xbf = (ushort_t*)((char*)d_ws + xbf_off);
    size_t need = xbf_off + (size_t)NNODES * DIM * sizeof(ushort_t);
    const int use_xbf = (ws_size >= need) ? 1 : 0;

    seg_bounds_k<<<(NSEG + 256) / 256, 256, 0, stream>>>(batch, seg, NNODES);
    wconv_k<<<(512 * 384) / 256, 256, 0, stream>>>(Wih, Whh, wbuf);

    dim3 ggrid(512 / 64, NSEG / 128);   // (8, 64)
    for (int t = 0; t < TSTEPS; ++t) {
        if (t > 0)
            gemm_mfma_k<<<ggrid, 256, 0, stream>>>(abuf, wbuf, gates);
        const int read_bf  = (use_xbf && t > 0) ? 1 : 0;
        const int write_bf = (use_xbf && t == 0) ? 1 : 0;
        attn_lstm_k<<<NSEG, 128, 0, stream>>>(x, xbf, seg, gates, bih, bhh,
                                              cbuf, out, abuf,
                                              (t == 0) ? 1 : 0, read_bf, write_bf);
    }
}